// Round 8
// baseline (339.096 us; speedup 1.0000x reference)
//
#include <hip/hip_runtime.h>
#include <stdint.h>

typedef __attribute__((ext_vector_type(8))) __bf16 bf16x8;
typedef __attribute__((ext_vector_type(16))) float f32x16;
typedef __attribute__((ext_vector_type(4))) float f32x4;
typedef __attribute__((ext_vector_type(2))) float f32x2;
typedef __attribute__((ext_vector_type(8))) unsigned short us8;

// ---------- helpers ----------
__device__ __forceinline__ unsigned short f2bf(float f) {
  unsigned u = __float_as_uint(f);
  unsigned r = u + 0x7fffu + ((u >> 16) & 1u);   // RNE
  return (unsigned short)(r >> 16);
}

__device__ __forceinline__ void gload16(const void* gptr, void* lptr) {
  __builtin_amdgcn_global_load_lds(
      (const __attribute__((address_space(1))) void*)gptr,
      (__attribute__((address_space(3))) void*)lptr, 16, 0, 0);
}

// ---------- prep: pack conv0 -> 32x32x16 MFMA B fragments (bf16) + wsum ----------
// bpack layout: [chunk(8)][tap(9)][c32g(16)][ks(4)][lane(64)][8] bf16
// frag(c32g, ks): lane l, elem e: co = c32g*32 + (l&31); ci = chunk*64 + ks*16 + (l>>5)*8 + e
__global__ void k_bpack(const float* __restrict__ conv0,
                        unsigned short* __restrict__ bpack,
                        float* __restrict__ wpart) {
  __shared__ float tile[64][65];
  int bx = blockIdx.x;                 // 576 = 9 taps * 8 chunks * 8 co-blocks(64)
  int tap = bx >> 6, rem = bx & 63;
  int chunk = rem >> 3, cob = rem & 7;
  int ci0 = chunk << 6, co0 = cob << 6;
  int ty = threadIdx.x >> 6, tx = threadIdx.x & 63;
#pragma unroll
  for (int k = 0; k < 16; ++k) {
    int ci = (k << 2) + ty;
    tile[ci][tx] = conv0[((size_t)(tap * 512 + ci0 + ci)) * 512 + co0 + tx];
  }
  __syncthreads();
  float p = 0.f;
#pragma unroll
  for (int q = 0; q < 16; ++q) {
    float v = tile[(ty << 4) + q][tx];
    p += v * v;
  }
  __shared__ float red[4][64];
  red[ty][tx] = p;
  __syncthreads();
  if (ty == 0)
    wpart[(size_t)(chunk * 9 + tap) * 512 + co0 + tx] =
        red[0][tx] + red[1][tx] + red[2][tx] + red[3][tx];
  // pack: slots = c32l(2) x ks(4) x lane(64) = 512, 2 per thread
#pragma unroll
  for (int s2 = 0; s2 < 2; ++s2) {
    int slot = (threadIdx.x << 1) + s2;
    int l = slot & 63;
    int ks = (slot >> 6) & 3;
    int c32l = slot >> 8;
    int col = (c32l << 5) + (l & 31);
    int cil = (ks << 4) + ((l >> 5) << 3);
    us8 o;
#pragma unroll
    for (int e = 0; e < 8; ++e) o[e] = f2bf(tile[cil + e][col]);
    int c32g = (cob << 1) + c32l;
    size_t fi = (((size_t)(chunk * 9 + tap) * 16 + c32g) * 4 + ks);
    *(us8*)(bpack + fi * 512 + (size_t)l * 8) = o;
  }
}

// ---------- prep: scale[b][co] = s0 * rsqrt(s0^2*wsum + 1e-8) ----------
__global__ void k_scale(const float* __restrict__ w, const float* __restrict__ y0k,
                        const float* __restrict__ y0b, const float* __restrict__ wpart,
                        float* __restrict__ scale) {
  int g = blockIdx.x * 256 + threadIdx.x;       // grid 16 -> 4096 = 8*512
  int b = g >> 9, co = g & 511;
  float s = y0b[co];
  const float* wr = w + b * 512;
  for (int ci = 0; ci < 512; ++ci) s += wr[ci] * y0k[ci * 512 + co];
  float ws = 0.f;
  for (int r = 0; r < 72; ++r) ws += wpart[(size_t)r * 512 + co];
  scale[g] = s * rsqrtf(s * s * ws + 1e-8f);
}

// ---------- prep: bilinear 2x upsample + zero-pad, f32 -> bf16 ----------
__global__ void k_up(const float* __restrict__ x, unsigned short* __restrict__ xpad) {
  int gid = blockIdx.x * 256 + threadIdx.x;     // total 8*66*66*64 = 2230272
  if (gid >= 8 * 66 * 66 * 64) return;
  int c0 = (gid & 63) << 3;
  int pos = gid >> 6;
  int xx = pos % 66;
  int t = pos / 66;
  int yy = t % 66;
  int b = t / 66;
  unsigned short* dst = xpad + (size_t)pos * 512 + c0;
  us8 o;
  if (yy == 0 || yy == 65 || xx == 0 || xx == 65) {
#pragma unroll
    for (int i = 0; i < 8; ++i) o[i] = 0;
  } else {
    int y = yy - 1, xq = xx - 1;
    int jy = y >> 1, jx = xq >> 1;
    int r0, r1, cx0, cx1;
    float ay0, ay1, ax0, ax1;
    if ((y & 1) == 0) { r0 = jy > 0 ? jy - 1 : 0; r1 = jy;
      ay0 = jy > 0 ? 0.25f : 0.f; ay1 = jy > 0 ? 0.75f : 1.f;
    } else { r0 = jy; r1 = jy < 31 ? jy + 1 : 31;
      ay0 = jy < 31 ? 0.75f : 1.f; ay1 = jy < 31 ? 0.25f : 0.f; }
    if ((xq & 1) == 0) { cx0 = jx > 0 ? jx - 1 : 0; cx1 = jx;
      ax0 = jx > 0 ? 0.25f : 0.f; ax1 = jx > 0 ? 0.75f : 1.f;
    } else { cx0 = jx; cx1 = jx < 31 ? jx + 1 : 31;
      ax0 = jx < 31 ? 0.75f : 1.f; ax1 = jx < 31 ? 0.25f : 0.f; }
    const float* base = x + (size_t)b * 32 * 32 * 512 + c0;
    const f32x4* q00 = (const f32x4*)(base + (size_t)(r0 * 32 + cx0) * 512);
    const f32x4* q01 = (const f32x4*)(base + (size_t)(r0 * 32 + cx1) * 512);
    const f32x4* q10 = (const f32x4*)(base + (size_t)(r1 * 32 + cx0) * 512);
    const f32x4* q11 = (const f32x4*)(base + (size_t)(r1 * 32 + cx1) * 512);
#pragma unroll
    for (int h = 0; h < 2; ++h) {
      f32x4 a = q00[h], bb = q01[h], c = q10[h], d = q11[h];
#pragma unroll
      for (int e = 0; e < 4; ++e) {
        float v = ay0 * (ax0 * a[e] + ax1 * bb[e]) + ay1 * (ax0 * c[e] + ax1 * d[e]);
        o[h * 4 + e] = f2bf(v);
      }
    }
  }
  *(us8*)dst = o;
}

// ---------- main conv: 32x32x16 MFMA, wide-N waves ----------
// Block 128px(2 rows) x 256co, 512 threads = 8 waves, wave = 32px x 128co
// (mi=1, ni=4). Per wave-tap: 4 ds_read_b128 (A) + 16 b128 global (B, L1-shared
// by 4 waves, ks-ping-pong regs) + 16 MFMA. Dbuf A halo (67.6 KB), 1 barrier
// per ci-chunk, 2 blocks/CU, grid 512 (2 rounds -> epilogue overlaps compute).
__global__ __launch_bounds__(512, 4) void k_conv(
    const unsigned short* __restrict__ xpad,
    const unsigned short* __restrict__ bpack,
    const float* __restrict__ scale,
    const float* __restrict__ noise,
    const float* __restrict__ ns0, const float* __restrict__ ns1,
    const float* __restrict__ bias0, const float* __restrict__ bias1,
    float* __restrict__ out)
{
  __shared__ __align__(16) unsigned short ldsA[2][16896];  // 2 x 33792 B

  const int tid = threadIdx.x;
  const int wid = tid >> 6;
  const int lane = tid & 63;
  const int l31 = lane & 31;
  const int lq = lane >> 5;            // 0/1

  // XCD-aware: XCD g = bx&7; XCD-pair shares nblk; contiguous 64-mblk run each
  const int bx = blockIdx.x;           // 512 = 256 mblk * 2 nblk
  const int g8 = bx & 7, j = bx >> 3;
  const int nblk = g8 & 1;
  const int mblk = ((g8 >> 1) << 6) + j;
  const int b = mblk >> 5;
  const int y0 = (mblk & 31) << 1;     // first of the block's 2 image rows

  const int wc = wid & 1;              // co-128 half
  const int xh32 = ((wid >> 1) & 1) << 5;  // px half within 64
  const int rb = wid >> 2;             // image row 0/1
  const int co_base = (nblk << 8) + (wc << 7);   // wave's 128-co slice

  f32x16 acc[4];
#pragma unroll
  for (int n = 0; n < 4; ++n)
#pragma unroll
    for (int e = 0; e < 16; ++e) acc[n][e] = 0.f;

  const size_t xb = (size_t)b * (66 * 66 * 512);
  // c32g base = nblk*8 + wc*4; frag(ni,ks) at wboff + ni*2048 + ks*512 elems
  const size_t wboff = ((size_t)((nblk << 3) + (wc << 2)) << 11) + (size_t)lane * 8;
  bf16x8 bqA[4], bqB[4];               // ks ping-pong: even ks -> A, odd -> B

  // staging: 2112 granules of 16B (4 rows x 66 px x 64 ci), slot-XOR swizzled
#define STAGE_A(DST, KC)                                                       \
  {                                                                            \
    _Pragma("unroll")                                                          \
    for (int it = 0; it < 5; ++it) {                                           \
      int g = it * 512 + tid;                                                  \
      if (it < 4 || tid < 64) {                                                \
        int rpx = g >> 3, sl = g & 7;                                          \
        int r = rpx / 66, px = rpx - r * 66;                                   \
        int ci = ((sl ^ (px & 7)) << 3) + (KC);                                \
        const unsigned short* src =                                            \
            xpad + xb + ((size_t)((y0 + r) * 66 + px) << 9) + ci;              \
        gload16(src, (char*)(DST) + (g << 4));                                 \
      }                                                                        \
    }                                                                          \
  }

  // ---- prologue: stage chunk 0, preload B(tap0, ks0) ----
  STAGE_A(ldsA[0], 0)
  {
    const unsigned short* wb = bpack + wboff;
#pragma unroll
    for (int ni = 0; ni < 4; ++ni)
      bqA[ni] = *(const bf16x8*)(wb + ni * 2048);
  }
  __syncthreads();

  for (int chunk = 0; chunk < 8; ++chunk) {
    const char* Acur = (const char*)ldsA[chunk & 1];
    const unsigned short* wb = bpack + (size_t)chunk * 294912 + wboff;

#pragma unroll
    for (int tap = 0; tap < 9; ++tap) {
      const int ky = tap / 3, kx = tap - ky * 3;
      const int r = rb + ky;
      const int px = xh32 + l31 + kx;
      const int rowoff = (r * 66 + px) << 7;
      const int psl = px & 7;
      // A fragments for all 4 ks
      bf16x8 af[4];
#pragma unroll
      for (int ks = 0; ks < 4; ++ks)
        af[ks] = *(const bf16x8*)(Acur + rowoff + ((((ks << 1) | lq) ^ psl) << 4));
      // issue next chunk's A staging during tap 0
      if (tap == 0 && chunk < 7) {
        char* Anxt = (char*)ldsA[(chunk + 1) & 1];
        const int kc = (chunk + 1) << 6;
        STAGE_A(Anxt, kc)
      }
#pragma unroll
      for (int ks = 0; ks < 4; ++ks) {
        bf16x8* cur = (ks & 1) ? bqB : bqA;
        bf16x8* nxt = (ks & 1) ? bqA : bqB;
        // prefetch next ks (or next tap / next chunk ks0)
        if (ks < 3) {
#pragma unroll
          for (int ni = 0; ni < 4; ++ni)
            nxt[ni] = *(const bf16x8*)(wb + tap * 32768 + ni * 2048 + (ks + 1) * 512);
        } else if (tap < 8) {
#pragma unroll
          for (int ni = 0; ni < 4; ++ni)
            nxt[ni] = *(const bf16x8*)(wb + (tap + 1) * 32768 + ni * 2048);
        } else if (chunk < 7) {
#pragma unroll
          for (int ni = 0; ni < 4; ++ni)
            nxt[ni] = *(const bf16x8*)(wb + 294912 + ni * 2048);
        }
        __builtin_amdgcn_s_setprio(1);
#pragma unroll
        for (int ni = 0; ni < 4; ++ni)
          acc[ni] = __builtin_amdgcn_mfma_f32_32x32x16_bf16(
              af[ks], cur[ni], acc[ni], 0, 0, 0);
        __builtin_amdgcn_s_setprio(0);
      }
    }
    __syncthreads();   // next-chunk A staged (vmcnt drain), all waves done w/ cur
  }

  // ---- epilogue: per-wave LDS transpose ([32px][66] f32, 8448 B/wave) ----
  // C/D 32x32: col = lane&31, row = (reg&3) + 8*(reg>>2) + 4*(lane>>5)
  __syncthreads();                     // all waves done reading halo LDS
  float* ldsE = (float*)ldsA + wid * 2112;
  float sc[4];
#pragma unroll
  for (int ni = 0; ni < 4; ++ni)
    sc[ni] = scale[(b << 9) + co_base + (ni << 5) + l31];
  const int qd = lane & 15;
  const int lhi = lane >> 4;
  const int row = y0 + rb;
#pragma unroll
  for (int p = 0; p < 2; ++p) {        // ni-pair pass: co p*64..p*64+63
#pragma unroll
    for (int n2 = 0; n2 < 2; ++n2) {
      int ni = (p << 1) + n2;
#pragma unroll
      for (int reg = 0; reg < 16; ++reg) {
        int pxrow = (reg & 3) + ((reg >> 2) << 3) + (lq << 2);
        ldsE[pxrow * 66 + (n2 << 5) + l31] = acc[ni][reg] * sc[ni];
      }
    }
    const int cpass = co_base + (p << 6);
    const f32x4 nz4 = *(const f32x4*)(noise + cpass + (qd << 2));
#pragma unroll
    for (int q = 0; q < 8; ++q) {
      int pxl = (q << 2) + lhi;        // 0..31
      int xcol = xh32 + pxl;
      f32x2 v01 = *(const f32x2*)(ldsE + pxl * 66 + (qd << 2));
      f32x2 v23 = *(const f32x2*)(ldsE + pxl * 66 + (qd << 2) + 2);
      size_t idx = (((size_t)((b << 6) + row) << 6) + xcol) * 512 + cpass + (qd << 2);
      f32x4 a0 = *(const f32x4*)(ns0 + idx);
      f32x4 b0 = *(const f32x4*)(bias0 + idx);
      f32x4 a1 = *(const f32x4*)(ns1 + idx);
      f32x4 b1 = *(const f32x4*)(bias1 + idx);
      f32x4 o;
      float vv[4] = {v01[0], v01[1], v23[0], v23[1]};
#pragma unroll
      for (int e = 0; e < 4; ++e) {
        float v0 = vv[e] + a0[e] * nz4[e] + b0[e];
        v0 = fmaxf(v0, 0.2f * v0);
        v0 = v0 + a1[e] * nz4[e] + b1[e];
        o[e] = fmaxf(v0, 0.2f * v0);
      }
      *(f32x4*)(out + idx) = o;
    }
  }
#undef STAGE_A
}

// ---------- launch ----------
extern "C" void kernel_launch(void* const* d_in, const int* in_sizes, int n_in,
                              void* d_out, int out_size, void* d_ws, size_t ws_size,
                              hipStream_t stream) {
  const float* x     = (const float*)d_in[0];
  const float* w     = (const float*)d_in[1];
  const float* noise = (const float*)d_in[2];
  const float* y0k   = (const float*)d_in[3];
  const float* y0b   = (const float*)d_in[4];
  // d_in[5..6]: y1_* unused (second conv result discarded by the reference).
  const float* conv0 = (const float*)d_in[7];
  // d_in[8]: conv1 unused
  const float* ns0   = (const float*)d_in[9];
  const float* ns1   = (const float*)d_in[10];
  const float* bias0 = (const float*)d_in[11];
  const float* bias1 = (const float*)d_in[12];
  float* out = (float*)d_out;

  char* ws = (char*)d_ws;
  unsigned short* xpad  = (unsigned short*)ws;
  unsigned short* bpack = (unsigned short*)(ws + 35684352);
  float* scale = (float*)(ws + 35684352 + 4718592);
  float* wpart = (float*)(ws + 35684352 + 4718592 + 16384);

  k_bpack<<<576, 256, 0, stream>>>(conv0, bpack, wpart);
  k_scale<<<16, 256, 0, stream>>>(w, y0k, y0b, wpart, scale);
  k_up<<<8712, 256, 0, stream>>>(x, xpad);
  k_conv<<<512, 512, 0, stream>>>(xpad, bpack, scale, noise, ns0, ns1, bias0, bias1, out);
}

// Round 9
// 231.432 us; speedup vs baseline: 1.4652x; 1.4652x over previous
//
#include <hip/hip_runtime.h>
#include <stdint.h>

typedef __attribute__((ext_vector_type(8))) __bf16 bf16x8;
typedef __attribute__((ext_vector_type(4))) float f32x4;
typedef __attribute__((ext_vector_type(2))) float f32x2;
typedef __attribute__((ext_vector_type(8))) unsigned short us8;

// ---------- helpers ----------
__device__ __forceinline__ unsigned short f2bf(float f) {
  unsigned u = __float_as_uint(f);
  unsigned r = u + 0x7fffu + ((u >> 16) & 1u);   // RNE
  return (unsigned short)(r >> 16);
}

__device__ __forceinline__ void gload16(const void* gptr, void* lptr) {
  __builtin_amdgcn_global_load_lds(
      (const __attribute__((address_space(1))) void*)gptr,
      (__attribute__((address_space(3))) void*)lptr, 16, 0, 0);
}

// ---------- prep: pack conv0 -> MFMA B fragments (bf16) + wsum partials ----------
// bpack layout: [T(72)][co16(32)][kk(2)][lane(64)][8] bf16, T = chunk*9+tap
// lane l, elem e: co = co16*16 + (l&15); ci = chunk*64 + kk*32 + (l>>4)*8 + e
__global__ void k_bpack(const float* __restrict__ conv0,
                        unsigned short* __restrict__ bpack,
                        float* __restrict__ wpart) {
  __shared__ float tile[64][65];
  int bx = blockIdx.x;                 // 576 = 9 taps * 8 chunks * 8 co-blocks
  int tap = bx >> 6, rem = bx & 63;
  int chunk = rem >> 3, cb = rem & 7;
  int ci0 = chunk << 6, co0 = cb << 6;
  int ty = threadIdx.x >> 6, tx = threadIdx.x & 63;
#pragma unroll
  for (int k = 0; k < 16; ++k) {
    int ci = (k << 2) + ty;
    tile[ci][tx] = conv0[((size_t)(tap * 512 + ci0 + ci)) * 512 + co0 + tx];
  }
  __syncthreads();
  float p = 0.f;
#pragma unroll
  for (int q = 0; q < 16; ++q) {
    float v = tile[(ty << 4) + q][tx];
    p += v * v;
  }
  __shared__ float red[4][64];
  red[ty][tx] = p;
  __syncthreads();
  if (ty == 0)
    wpart[(size_t)(chunk * 9 + tap) * 512 + co0 + tx] =
        red[0][tx] + red[1][tx] + red[2][tx] + red[3][tx];
#pragma unroll
  for (int s2 = 0; s2 < 2; ++s2) {
    int slot = (threadIdx.x << 1) + s2;
    int f = slot >> 6, l = slot & 63;
    int co16l = f >> 1, kk = f & 1;
    int col = (co16l << 4) + (l & 15);
    int cil = (kk << 5) + ((l >> 4) << 3);
    us8 o;
#pragma unroll
    for (int e = 0; e < 8; ++e) o[e] = f2bf(tile[cil + e][col]);
    size_t fi = (((size_t)(chunk * 9 + tap) * 32 + (cb << 2) + co16l) << 1) + kk;
    *(us8*)(bpack + fi * 512 + (size_t)l * 8) = o;
  }
}

// ---------- prep: scale[b][co] = s0 * rsqrt(s0^2*wsum + 1e-8) ----------
__global__ void k_scale(const float* __restrict__ w, const float* __restrict__ y0k,
                        const float* __restrict__ y0b, const float* __restrict__ wpart,
                        float* __restrict__ scale) {
  int g = blockIdx.x * 256 + threadIdx.x;       // grid 16 -> 4096 = 8*512
  int b = g >> 9, co = g & 511;
  float s = y0b[co];
  const float* wr = w + b * 512;
  for (int ci = 0; ci < 512; ++ci) s += wr[ci] * y0k[ci * 512 + co];
  float ws = 0.f;
  for (int r = 0; r < 72; ++r) ws += wpart[(size_t)r * 512 + co];
  scale[g] = s * rsqrtf(s * s * ws + 1e-8f);
}

// ---------- prep: bilinear 2x upsample + zero-pad, f32 -> bf16 ----------
__global__ void k_up(const float* __restrict__ x, unsigned short* __restrict__ xpad) {
  int gid = blockIdx.x * 256 + threadIdx.x;     // total 8*66*66*64 = 2230272
  if (gid >= 8 * 66 * 66 * 64) return;
  int c0 = (gid & 63) << 3;
  int pos = gid >> 6;
  int xx = pos % 66;
  int t = pos / 66;
  int yy = t % 66;
  int b = t / 66;
  unsigned short* dst = xpad + (size_t)pos * 512 + c0;
  us8 o;
  if (yy == 0 || yy == 65 || xx == 0 || xx == 65) {
#pragma unroll
    for (int i = 0; i < 8; ++i) o[i] = 0;
  } else {
    int y = yy - 1, xq = xx - 1;
    int jy = y >> 1, jx = xq >> 1;
    int r0, r1, cx0, cx1;
    float ay0, ay1, ax0, ax1;
    if ((y & 1) == 0) { r0 = jy > 0 ? jy - 1 : 0; r1 = jy;
      ay0 = jy > 0 ? 0.25f : 0.f; ay1 = jy > 0 ? 0.75f : 1.f;
    } else { r0 = jy; r1 = jy < 31 ? jy + 1 : 31;
      ay0 = jy < 31 ? 0.75f : 1.f; ay1 = jy < 31 ? 0.25f : 0.f; }
    if ((xq & 1) == 0) { cx0 = jx > 0 ? jx - 1 : 0; cx1 = jx;
      ax0 = jx > 0 ? 0.25f : 0.f; ax1 = jx > 0 ? 0.75f : 1.f;
    } else { cx0 = jx; cx1 = jx < 31 ? jx + 1 : 31;
      ax0 = jx < 31 ? 0.75f : 1.f; ax1 = jx < 31 ? 0.25f : 0.f; }
    const float* base = x + (size_t)b * 32 * 32 * 512 + c0;
    const f32x4* q00 = (const f32x4*)(base + (size_t)(r0 * 32 + cx0) * 512);
    const f32x4* q01 = (const f32x4*)(base + (size_t)(r0 * 32 + cx1) * 512);
    const f32x4* q10 = (const f32x4*)(base + (size_t)(r1 * 32 + cx0) * 512);
    const f32x4* q11 = (const f32x4*)(base + (size_t)(r1 * 32 + cx1) * 512);
#pragma unroll
    for (int h = 0; h < 2; ++h) {
      f32x4 a = q00[h], bb = q01[h], c = q10[h], d = q11[h];
#pragma unroll
      for (int e = 0; e < 4; ++e) {
        float v = ay0 * (ax0 * a[e] + ax1 * bb[e]) + ay1 * (ax0 * c[e] + ax1 * d[e]);
        o[h * 4 + e] = f2bf(v);
      }
    }
  }
  *(us8*)dst = o;
}

// ---------- main conv: deep-pipelined (af dbuf, B 2-taps-deep) ----------
// Block 128px(2 rows) x 128co; 4 waves 2x2: wave = 64px(1 row) x 64co
// (mi=4, ni=4). Occupancy is LDS-bound at 2 waves/SIMD -> spend VGPRs on
// pipeline depth: af[8] double-buffered across taps (LDS latency hidden),
// bq 3 rotating buffers = 2 taps of B prefetch (L2 latency hidden).
__global__ __launch_bounds__(256, 2) void k_conv(
    const unsigned short* __restrict__ xpad,
    const unsigned short* __restrict__ bpack,
    const float* __restrict__ scale,
    const float* __restrict__ noise,
    const float* __restrict__ ns0, const float* __restrict__ ns1,
    const float* __restrict__ bias0, const float* __restrict__ bias1,
    float* __restrict__ out)
{
  __shared__ __align__(16) unsigned short ldsA[2][16896];  // 2 x 33 KiB

  const int tid = threadIdx.x;
  const int wid = tid >> 6;
  const int lane = tid & 63;
  const int l15 = lane & 15, lhi = lane >> 4;

  const int bx = blockIdx.x;           // 1024
  const int nblk = (bx >> 1) & 3;
  const int mblk = ((bx >> 3) << 1) | (bx & 1);
  const int b = mblk >> 5;
  const int y0 = (mblk & 31) << 1;
  const int wr = wid >> 1, wc = wid & 1;
  const int co_base = (nblk << 7) + (wc << 6);   // wave's 64-co slice

  f32x4 acc[4][4];
#pragma unroll
  for (int i = 0; i < 4; ++i)
#pragma unroll
    for (int j = 0; j < 4; ++j) acc[i][j] = f32x4{0.f, 0.f, 0.f, 0.f};

  const size_t xb = (size_t)b * (66 * 66 * 512);
  // wave's B slice: co16 base = nblk*8 + wc*4; frag(T,ni,kk) at
  // wbase + T*32768 + ni*1024 + kk*512 (elems)
  const unsigned short* wbase =
      bpack + ((size_t)((nblk << 3) + (wc << 2)) << 10) + (size_t)lane * 8;

  bf16x8 afA[8], afB[8];               // af double-buffer (tap parity)
  bf16x8 bqA[8], bqB[8], bqC[8];       // B 3-rotation (tap % 3)

#define LOAD_BQ(DST, T)                                                        \
  {                                                                            \
    const unsigned short* wp = wbase + (size_t)(T) * 32768;                    \
    _Pragma("unroll")                                                          \
    for (int ni = 0; ni < 4; ++ni) {                                           \
      _Pragma("unroll")                                                        \
      for (int kk = 0; kk < 2; ++kk)                                           \
        (DST)[ni * 2 + kk] = *(const bf16x8*)(wp + ni * 1024 + kk * 512);      \
    }                                                                          \
  }

#define LOAD_AF(DST, TAP)                                                      \
  {                                                                            \
    const int ky_ = (TAP) / 3, kx_ = (TAP) - ky_ * 3;                          \
    const int r_ = wr + ky_;                                                   \
    const int axor_ = ((l15 + kx_) & 7) << 4;                                  \
    _Pragma("unroll")                                                          \
    for (int kk = 0; kk < 2; ++kk) {                                           \
      const int kbyte_ = (((kk << 5) + (lhi << 3)) << 1);                      \
      _Pragma("unroll")                                                        \
      for (int mi = 0; mi < 4; ++mi) {                                         \
        int xx_ = (mi << 4) + l15 + kx_;                                       \
        int off_ = ((r_ * 66 + xx_) << 7) + (kbyte_ ^ axor_);                  \
        (DST)[kk * 4 + mi] = *(const bf16x8*)(Acur + off_);                    \
      }                                                                        \
    }                                                                          \
  }

  // ---- prologue: stage chunk 0; preload B for T=0,1 ----
  {
#pragma unroll
    for (int i = wid; i < 33; i += 4) {
      int g = (i << 6) + lane;
      int rx = g >> 3;
      int r = rx / 66;
      int xx = rx - r * 66;
      int cg = (g & 7) ^ (xx & 7);
      const unsigned short* src =
          xpad + xb + ((size_t)((y0 + r) * 66 + xx) << 9) + (cg << 3);
      gload16(src, (char*)ldsA[0] + (i << 10));
    }
    LOAD_BQ(bqA, 0)
    LOAD_BQ(bqB, 1)
  }
  __syncthreads();

  for (int chunk = 0; chunk < 8; ++chunk) {
    const char* Acur = (const char*)ldsA[chunk & 1];
    const bool last = (chunk == 7);

    // tap 0's A fragments (fresh buffer after barrier)
    LOAD_AF(afA, 0)

#pragma unroll
    for (int t = 0; t < 9; ++t) {
      bf16x8* afC = (t & 1) ? afB : afA;
      bf16x8* afN = (t & 1) ? afA : afB;
      bf16x8* bqc = (t % 3 == 0) ? bqA : (t % 3 == 1) ? bqB : bqC;
      bf16x8* bqn = ((t + 2) % 3 == 0) ? bqA : ((t + 2) % 3 == 1) ? bqB : bqC;

      // issue next chunk's A staging during tap 0
      if (t == 0 && !last) {
        char* Anxt = (char*)ldsA[(chunk + 1) & 1];
        const int kc = (chunk + 1) << 6;
#pragma unroll
        for (int i = wid; i < 33; i += 4) {
          int g = (i << 6) + lane;
          int rx = g >> 3;
          int r = rx / 66;
          int xx = rx - r * 66;
          int cg = (g & 7) ^ (xx & 7);
          const unsigned short* src =
              xpad + xb + ((size_t)((y0 + r) * 66 + xx) << 9) + kc + (cg << 3);
          gload16(src, Anxt + (i << 10));
        }
      }
      // B prefetch 2 taps ahead (crosses chunk boundary via linear T)
      if (t < 7 || !last) {
        LOAD_BQ(bqn, chunk * 9 + t + 2)
      }
      // af prefetch for next tap (same chunk buffer)
      if (t < 8) {
        LOAD_AF(afN, t + 1)
      }
      // MFMA cluster on fully-prefetched operands
      __builtin_amdgcn_s_setprio(1);
#pragma unroll
      for (int kk = 0; kk < 2; ++kk)
#pragma unroll
        for (int mi = 0; mi < 4; ++mi)
#pragma unroll
          for (int ni = 0; ni < 4; ++ni)
            acc[mi][ni] = __builtin_amdgcn_mfma_f32_16x16x32_bf16(
                afC[kk * 4 + mi], bqc[ni * 2 + kk], acc[mi][ni], 0, 0, 0);
      __builtin_amdgcn_s_setprio(0);
    }
    __syncthreads();   // next-chunk A staged (vmcnt drain), all waves done w/ cur
  }

  // ---- epilogue: per-wave LDS transpose (64px x 64co, stride-66 f32) ----
  float* ldsE = (float*)ldsA + wid * 4224;   // 64*66 floats per wave (16.5 KiB)
  float sc[4];
#pragma unroll
  for (int ni = 0; ni < 4; ++ni)
    sc[ni] = scale[(b << 9) + co_base + (ni << 4) + l15];
#pragma unroll
  for (int mi = 0; mi < 4; ++mi)
#pragma unroll
    for (int ni = 0; ni < 4; ++ni)
#pragma unroll
      for (int j = 0; j < 4; ++j) {
        int px = (mi << 4) + (lhi << 2) + j;
        ldsE[px * 66 + (ni << 4) + l15] = acc[mi][ni][j] * sc[ni];
      }
  const int qd = l15;                  // co quad 0..15 -> 64 co
  const int py = y0 + wr;
  const f32x4 nz4 = *(const f32x4*)(noise + co_base + (qd << 2));
#pragma unroll
  for (int q = 0; q < 16; ++q) {
    int px = (q << 2) + lhi;           // xcol 0..63
    f32x2 v01 = *(const f32x2*)(ldsE + px * 66 + (qd << 2));
    f32x2 v23 = *(const f32x2*)(ldsE + px * 66 + (qd << 2) + 2);
    size_t idx = (((size_t)((b << 6) + py) << 6) + px) * 512 + co_base + (qd << 2);
    f32x4 a0 = *(const f32x4*)(ns0 + idx);
    f32x4 b0 = *(const f32x4*)(bias0 + idx);
    f32x4 a1 = *(const f32x4*)(ns1 + idx);
    f32x4 b1 = *(const f32x4*)(bias1 + idx);
    f32x4 o;
    float vv[4] = {v01[0], v01[1], v23[0], v23[1]};
#pragma unroll
    for (int e = 0; e < 4; ++e) {
      float v0 = vv[e] + a0[e] * nz4[e] + b0[e];
      v0 = fmaxf(v0, 0.2f * v0);
      v0 = v0 + a1[e] * nz4[e] + b1[e];
      o[e] = fmaxf(v0, 0.2f * v0);
    }
    *(f32x4*)(out + idx) = o;
  }
#undef LOAD_BQ
#undef LOAD_AF
}

// ---------- launch ----------
extern "C" void kernel_launch(void* const* d_in, const int* in_sizes, int n_in,
                              void* d_out, int out_size, void* d_ws, size_t ws_size,
                              hipStream_t stream) {
  const float* x     = (const float*)d_in[0];
  const float* w     = (const float*)d_in[1];
  const float* noise = (const float*)d_in[2];
  const float* y0k   = (const float*)d_in[3];
  const float* y0b   = (const float*)d_in[4];
  // d_in[5..6]: y1_* unused (second conv result discarded by the reference).
  const float* conv0 = (const float*)d_in[7];
  // d_in[8]: conv1 unused
  const float* ns0   = (const float*)d_in[9];
  const float* ns1   = (const float*)d_in[10];
  const float* bias0 = (const float*)d_in[11];
  const float* bias1 = (const float*)d_in[12];
  float* out = (float*)d_out;

  char* ws = (char*)d_ws;
  unsigned short* xpad  = (unsigned short*)ws;
  unsigned short* bpack = (unsigned short*)(ws + 35684352);
  float* scale = (float*)(ws + 35684352 + 4718592);
  float* wpart = (float*)(ws + 35684352 + 4718592 + 16384);

  k_bpack<<<576, 256, 0, stream>>>(conv0, bpack, wpart);
  k_scale<<<16, 256, 0, stream>>>(w, y0k, y0b, wpart, scale);
  k_up<<<8712, 256, 0, stream>>>(x, xpad);
  k_conv<<<1024, 256, 0, stream>>>(xpad, bpack, scale, noise, ns0, ns1, bias0, bias1, out);
}

// Round 11
// 214.333 us; speedup vs baseline: 1.5821x; 1.0798x over previous
//
#include <hip/hip_runtime.h>
#include <stdint.h>

typedef __attribute__((ext_vector_type(8))) __bf16 bf16x8;
typedef __attribute__((ext_vector_type(4))) float f32x4;
typedef __attribute__((ext_vector_type(2))) float f32x2;
typedef __attribute__((ext_vector_type(8))) unsigned short us8;

// ---------- helpers ----------
__device__ __forceinline__ unsigned short f2bf(float f) {
  unsigned u = __float_as_uint(f);
  unsigned r = u + 0x7fffu + ((u >> 16) & 1u);   // RNE
  return (unsigned short)(r >> 16);
}

__device__ __forceinline__ void gload16(const void* gptr, void* lptr) {
  __builtin_amdgcn_global_load_lds(
      (const __attribute__((address_space(1))) void*)gptr,
      (__attribute__((address_space(3))) void*)lptr, 16, 0, 0);
}

// ---------- prep: pack conv0 -> MFMA B fragments (bf16) + wsum partials ----------
// bpack layout: [T(72)][co16(32)][kk(2)][lane(64)][8] bf16, T = chunk*9+tap
// lane l, elem e: co = co16*16 + (l&15); ci = chunk*64 + kk*32 + (l>>4)*8 + e
__global__ void k_bpack(const float* __restrict__ conv0,
                        unsigned short* __restrict__ bpack,
                        float* __restrict__ wpart) {
  __shared__ float tile[64][65];
  int bx = blockIdx.x;                 // 576 = 9 taps * 8 chunks * 8 co-blocks
  int tap = bx >> 6, rem = bx & 63;
  int chunk = rem >> 3, cb = rem & 7;
  int ci0 = chunk << 6, co0 = cb << 6;
  int ty = threadIdx.x >> 6, tx = threadIdx.x & 63;
#pragma unroll
  for (int k = 0; k < 16; ++k) {
    int ci = (k << 2) + ty;
    tile[ci][tx] = conv0[((size_t)(tap * 512 + ci0 + ci)) * 512 + co0 + tx];
  }
  __syncthreads();
  float p = 0.f;
#pragma unroll
  for (int q = 0; q < 16; ++q) {
    float v = tile[(ty << 4) + q][tx];
    p += v * v;
  }
  __shared__ float red[4][64];
  red[ty][tx] = p;
  __syncthreads();
  if (ty == 0)
    wpart[(size_t)(chunk * 9 + tap) * 512 + co0 + tx] =
        red[0][tx] + red[1][tx] + red[2][tx] + red[3][tx];
#pragma unroll
  for (int s2 = 0; s2 < 2; ++s2) {
    int slot = (threadIdx.x << 1) + s2;
    int f = slot >> 6, l = slot & 63;
    int co16l = f >> 1, kk = f & 1;
    int col = (co16l << 4) + (l & 15);
    int cil = (kk << 5) + ((l >> 4) << 3);
    us8 o;
#pragma unroll
    for (int e = 0; e < 8; ++e) o[e] = f2bf(tile[cil + e][col]);
    size_t fi = (((size_t)(chunk * 9 + tap) * 32 + (cb << 2) + co16l) << 1) + kk;
    *(us8*)(bpack + fi * 512 + (size_t)l * 8) = o;
  }
}

// ---------- prep: scale[b][co] = s0 * rsqrt(s0^2*wsum + 1e-8) ----------
__global__ void k_scale(const float* __restrict__ w, const float* __restrict__ y0k,
                        const float* __restrict__ y0b, const float* __restrict__ wpart,
                        float* __restrict__ scale) {
  int g = blockIdx.x * 256 + threadIdx.x;       // grid 16 -> 4096 = 8*512
  int b = g >> 9, co = g & 511;
  float s = y0b[co];
  const float* wr = w + b * 512;
  for (int ci = 0; ci < 512; ++ci) s += wr[ci] * y0k[ci * 512 + co];
  float ws = 0.f;
  for (int r = 0; r < 72; ++r) ws += wpart[(size_t)r * 512 + co];
  scale[g] = s * rsqrtf(s * s * ws + 1e-8f);
}

// ---------- prep: bilinear 2x upsample + zero-pad, f32 -> bf16 ----------
__global__ void k_up(const float* __restrict__ x, unsigned short* __restrict__ xpad) {
  int gid = blockIdx.x * 256 + threadIdx.x;     // total 8*66*66*64 = 2230272
  if (gid >= 8 * 66 * 66 * 64) return;
  int c0 = (gid & 63) << 3;
  int pos = gid >> 6;
  int xx = pos % 66;
  int t = pos / 66;
  int yy = t % 66;
  int b = t / 66;
  unsigned short* dst = xpad + (size_t)pos * 512 + c0;
  us8 o;
  if (yy == 0 || yy == 65 || xx == 0 || xx == 65) {
#pragma unroll
    for (int i = 0; i < 8; ++i) o[i] = 0;
  } else {
    int y = yy - 1, xq = xx - 1;
    int jy = y >> 1, jx = xq >> 1;
    int r0, r1, cx0, cx1;
    float ay0, ay1, ax0, ax1;
    if ((y & 1) == 0) { r0 = jy > 0 ? jy - 1 : 0; r1 = jy;
      ay0 = jy > 0 ? 0.25f : 0.f; ay1 = jy > 0 ? 0.75f : 1.f;
    } else { r0 = jy; r1 = jy < 31 ? jy + 1 : 31;
      ay0 = jy < 31 ? 0.75f : 1.f; ay1 = jy < 31 ? 0.25f : 0.f; }
    if ((xq & 1) == 0) { cx0 = jx > 0 ? jx - 1 : 0; cx1 = jx;
      ax0 = jx > 0 ? 0.25f : 0.f; ax1 = jx > 0 ? 0.75f : 1.f;
    } else { cx0 = jx; cx1 = jx < 31 ? jx + 1 : 31;
      ax0 = jx < 31 ? 0.75f : 1.f; ax1 = jx < 31 ? 0.25f : 0.f; }
    const float* base = x + (size_t)b * 32 * 32 * 512 + c0;
    const f32x4* q00 = (const f32x4*)(base + (size_t)(r0 * 32 + cx0) * 512);
    const f32x4* q01 = (const f32x4*)(base + (size_t)(r0 * 32 + cx1) * 512);
    const f32x4* q10 = (const f32x4*)(base + (size_t)(r1 * 32 + cx0) * 512);
    const f32x4* q11 = (const f32x4*)(base + (size_t)(r1 * 32 + cx1) * 512);
#pragma unroll
    for (int h = 0; h < 2; ++h) {
      f32x4 a = q00[h], bb = q01[h], c = q10[h], d = q11[h];
#pragma unroll
      for (int e = 0; e < 4; ++e) {
        float v = ay0 * (ax0 * a[e] + ax1 * bb[e]) + ay1 * (ax0 * c[e] + ax1 * d[e]);
        o[h * 4 + e] = f2bf(v);
      }
    }
  }
  *(us8*)dst = o;
}

// ---------- main conv: phase-locked taps, raw barriers, counted vmcnt ----------
// Block 128px(2 rows) x 128co; 4 waves 2x2: wave = 64px(1 row) x 64co
// (mi=4, ni=4). Chunks processed in PAIRS (18 taps, even) so the bq ping-pong
// parity (t&1) is consistent across chunk boundaries (R10's bug: 9 is odd).
// Per tap-phase: {ds_read af(t) | global bq(T+1) | tap0/9: staging issue}
// -> s_barrier -> 32 MFMA -> s_barrier. vmcnt NEVER drained to 0 in the loop;
// chunk ends use counted vmcnt(8) (staging pinned oldest via sched_barrier).
__global__ __launch_bounds__(256, 2) void k_conv(
    const unsigned short* __restrict__ xpad,
    const unsigned short* __restrict__ bpack,
    const float* __restrict__ scale,
    const float* __restrict__ noise,
    const float* __restrict__ ns0, const float* __restrict__ ns1,
    const float* __restrict__ bias0, const float* __restrict__ bias1,
    float* __restrict__ out)
{
  __shared__ __align__(16) unsigned short ldsA[2][16896];  // 2 x 33 KiB

  const int tid = threadIdx.x;
  const int wid = tid >> 6;
  const int lane = tid & 63;
  const int l15 = lane & 15, lhi = lane >> 4;

  const int bx = blockIdx.x;           // 1024
  const int nblk = (bx >> 1) & 3;
  const int mblk = ((bx >> 3) << 1) | (bx & 1);
  const int b = mblk >> 5;
  const int y0 = (mblk & 31) << 1;
  const int wr = wid >> 1, wc = wid & 1;
  const int co_base = (nblk << 7) + (wc << 6);   // wave's 64-co slice

  f32x4 acc[4][4];
#pragma unroll
  for (int i = 0; i < 4; ++i)
#pragma unroll
    for (int j = 0; j < 4; ++j) acc[i][j] = f32x4{0.f, 0.f, 0.f, 0.f};

  const size_t xb = (size_t)b * (66 * 66 * 512);
  // frag(T,ni,kk) at wbase + T*32768 + ni*1024 + kk*512 (elems)
  const unsigned short* wbase =
      bpack + ((size_t)((nblk << 3) + (wc << 2)) << 10) + (size_t)lane * 8;

  bf16x8 af[8];                        // same-phase consumption
  bf16x8 bq0[8], bq1[8];               // 1-tap-deep ping-pong (t&1, 18-even)

#define LOAD_BQ(DST, T)                                                        \
  {                                                                            \
    const unsigned short* wp = wbase + (size_t)(T) * 32768;                    \
    _Pragma("unroll")                                                          \
    for (int ni = 0; ni < 4; ++ni) {                                           \
      _Pragma("unroll")                                                        \
      for (int kk = 0; kk < 2; ++kk)                                           \
        (DST)[ni * 2 + kk] = *(const bf16x8*)(wp + ni * 1024 + kk * 512);      \
    }                                                                          \
  }

#define LOAD_AF(ACUR, TAP)                                                     \
  {                                                                            \
    const int ky_ = (TAP) / 3, kx_ = (TAP) - ky_ * 3;                          \
    const int r_ = wr + ky_;                                                   \
    const int axor_ = ((l15 + kx_) & 7) << 4;                                  \
    _Pragma("unroll")                                                          \
    for (int kk = 0; kk < 2; ++kk) {                                           \
      const int kbyte_ = (((kk << 5) + (lhi << 3)) << 1);                      \
      _Pragma("unroll")                                                        \
      for (int mi = 0; mi < 4; ++mi) {                                         \
        int xx_ = (mi << 4) + l15 + kx_;                                       \
        int off_ = ((r_ * 66 + xx_) << 7) + (kbyte_ ^ axor_);                  \
        af[kk * 4 + mi] = *(const bf16x8*)((ACUR) + off_);                     \
      }                                                                        \
    }                                                                          \
  }

#define STAGE_A(DST, KC)                                                       \
  {                                                                            \
    _Pragma("unroll")                                                          \
    for (int i = wid; i < 33; i += 4) {                                        \
      int g = (i << 6) + lane;                                                 \
      int rx = g >> 3;                                                         \
      int r = rx / 66;                                                         \
      int xx = rx - r * 66;                                                    \
      int cg = (g & 7) ^ (xx & 7);                                             \
      const unsigned short* src =                                              \
          xpad + xb + ((size_t)((y0 + r) * 66 + xx) << 9) + (KC) + (cg << 3);  \
      gload16(src, (char*)(DST) + (i << 10));                                  \
    }                                                                          \
  }

  // ---- prologue: stage chunk 0 into ldsA[0]; preload B(T=0) ----
  STAGE_A(ldsA[0], 0)
  LOAD_BQ(bq0, 0)
  __syncthreads();

  for (int cp = 0; cp < 4; ++cp) {     // chunk pair: chunks 2cp, 2cp+1
    const int Tbase = cp * 18;

#pragma unroll
    for (int t = 0; t < 18; ++t) {
      const int tap = (t < 9) ? t : t - 9;
      const char* Acur = (const char*)ldsA[(t < 9) ? 0 : 1];
      bf16x8* cur = (t & 1) ? bq1 : bq0;
      bf16x8* nxt = (t & 1) ? bq0 : bq1;

      // ---- issue phase ----
      LOAD_AF(Acur, tap)
      const int T2 = Tbase + t + 1;
      if (T2 < 72) {
        LOAD_BQ(nxt, T2)
      }
      if (t == 0) {
        // stage chunk 2cp+1 into ldsA[1]
        STAGE_A(ldsA[1], (cp * 2 + 1) << 6)
        __builtin_amdgcn_sched_barrier(0);   // pin staging oldest-in-queue
      }
      if (t == 9 && cp < 3) {
        // stage chunk 2cp+2 into ldsA[0]
        STAGE_A(ldsA[0], (cp * 2 + 2) << 6)
        __builtin_amdgcn_sched_barrier(0);
      }
      __builtin_amdgcn_s_barrier();          // align waves; NO vmcnt drain
      // ---- compute phase (compiler inserts lgkm wait for af) ----
      __builtin_amdgcn_s_setprio(1);
#pragma unroll
      for (int kk = 0; kk < 2; ++kk)
#pragma unroll
        for (int mi = 0; mi < 4; ++mi)
#pragma unroll
          for (int ni = 0; ni < 4; ++ni)
            acc[mi][ni] = __builtin_amdgcn_mfma_f32_16x16x32_bf16(
                af[kk * 4 + mi], cur[ni * 2 + kk], acc[mi][ni], 0, 0, 0);
      __builtin_amdgcn_s_setprio(0);
      if (tap == 8) {
        // chunk end: own staging (oldest) must have landed; keep the 8
        // just-issued B loads in flight
        asm volatile("s_waitcnt vmcnt(8)" ::: "memory");
      }
      __builtin_amdgcn_s_barrier();
    }
  }

  // ---- epilogue: per-wave LDS transpose (64px x 64co, stride-66 f32) ----
  __syncthreads();                     // full drain before LDS reuse
  float* ldsE = (float*)ldsA + wid * 4224;   // 64*66 floats per wave (16.5 KiB)
  float sc[4];
#pragma unroll
  for (int ni = 0; ni < 4; ++ni)
    sc[ni] = scale[(b << 9) + co_base + (ni << 4) + l15];
#pragma unroll
  for (int mi = 0; mi < 4; ++mi)
#pragma unroll
    for (int ni = 0; ni < 4; ++ni)
#pragma unroll
      for (int j = 0; j < 4; ++j) {
        int px = (mi << 4) + (lhi << 2) + j;
        ldsE[px * 66 + (ni << 4) + l15] = acc[mi][ni][j] * sc[ni];
      }
  const int qd = l15;                  // co quad 0..15 -> 64 co
  const int py = y0 + wr;
  const f32x4 nz4 = *(const f32x4*)(noise + co_base + (qd << 2));
#pragma unroll
  for (int q = 0; q < 16; ++q) {
    int px = (q << 2) + lhi;           // xcol 0..63
    f32x2 v01 = *(const f32x2*)(ldsE + px * 66 + (qd << 2));
    f32x2 v23 = *(const f32x2*)(ldsE + px * 66 + (qd << 2) + 2);
    size_t idx = (((size_t)((b << 6) + py) << 6) + px) * 512 + co_base + (qd << 2);
    f32x4 a0 = *(const f32x4*)(ns0 + idx);
    f32x4 b0 = *(const f32x4*)(bias0 + idx);
    f32x4 a1 = *(const f32x4*)(ns1 + idx);
    f32x4 b1 = *(const f32x4*)(bias1 + idx);
    f32x4 o;
    float vv[4] = {v01[0], v01[1], v23[0], v23[1]};
#pragma unroll
    for (int e = 0; e < 4; ++e) {
      float v0 = vv[e] + a0[e] * nz4[e] + b0[e];
      v0 = fmaxf(v0, 0.2f * v0);
      v0 = v0 + a1[e] * nz4[e] + b1[e];
      o[e] = fmaxf(v0, 0.2f * v0);
    }
    *(f32x4*)(out + idx) = o;
  }
#undef LOAD_BQ
#undef LOAD_AF
#undef STAGE_A
}

// ---------- launch ----------
extern "C" void kernel_launch(void* const* d_in, const int* in_sizes, int n_in,
                              void* d_out, int out_size, void* d_ws, size_t ws_size,
                              hipStream_t stream) {
  const float* x     = (const float*)d_in[0];
  const float* w     = (const float*)d_in[1];
  const float* noise = (const float*)d_in[2];
  const float* y0k   = (const float*)d_in[3];
  const float* y0b   = (const float*)d_in[4];
  // d_in[5..6]: y1_* unused (second conv result discarded by the reference).
  const float* conv0 = (const float*)d_in[7];
  // d_in[8]: conv1 unused
  const float* ns0   = (const float*)d_in[9];
  const float* ns1   = (const float*)d_in[10];
  const float* bias0 = (const float*)d_in[11];
  const float* bias1 = (const float*)d_in[12];
  float* out = (float*)d_out;

  char* ws = (char*)d_ws;
  unsigned short* xpad  = (unsigned short*)ws;
  unsigned short* bpack = (unsigned short*)(ws + 35684352);
  float* scale = (float*)(ws + 35684352 + 4718592);
  float* wpart = (float*)(ws + 35684352 + 4718592 + 16384);

  k_bpack<<<576, 256, 0, stream>>>(conv0, bpack, wpart);
  k_scale<<<16, 256, 0, stream>>>(w, y0k, y0b, wpart, scale);
  k_up<<<8712, 256, 0, stream>>>(x, xpad);
  k_conv<<<1024, 256, 0, stream>>>(xpad, bpack, scale, noise, ns0, ns1, bias0, bias1, out);
}